// Round 1
// baseline (404.032 us; speedup 1.0000x reference)
//
#include <hip/hip_runtime.h>
#include <hip/hip_bf16.h>

// Problem constants (fixed by the reference): T=52, N=1000, D=2, G=150, H=50
#define T_   52
#define N_   1000
#define D_   2
#define G_   150
#define H_   50
#define TM2  (T_ - 2)        // 50
#define ND   (N_ * D_)       // 2000
#define TND  (T_ * N_ * D_)  // 104000
#define GB   5               // g-values per block (G_ % GB == 0)
#define NCHUNK (G_ / GB)     // 30

typedef unsigned short ushort8_t __attribute__((ext_vector_type(8))); // 16 B
typedef float          float8_t  __attribute__((ext_vector_type(8))); // 32 B

__device__ __forceinline__ float bf2f(unsigned short u) {
    return __uint_as_float(((unsigned)u) << 16);
}
__device__ __forceinline__ unsigned short f2bf(float f) {
    unsigned u = __float_as_uint(f);
    u += 0x7fffu + ((u >> 16) & 1u);   // round-to-nearest-even
    return (unsigned short)(u >> 16);
}

// dtype-dispatched scalar load
template<bool F32>
__device__ __forceinline__ float ld1(const void* p, int i) {
    if constexpr (F32) return ((const float*)p)[i];
    else               return bf2f(((const unsigned short*)p)[i]);
}

// dtype-dispatched 8-element vector load (f32: 32B = 2x dwordx4; bf16: 16B)
template<bool F32>
__device__ __forceinline__ float8_t ld8(const void* p, int i) {
    if constexpr (F32) {
        return *(const float8_t*)((const float*)p + i);
    } else {
        ushort8_t v = *(const ushort8_t*)((const unsigned short*)p + i);
        float8_t r;
#pragma unroll
        for (int j = 0; j < 8; ++j) r[j] = bf2f(v[j]);
        return r;
    }
}

// ---------------- Kernel 1: scalar MLPs -> drift, Dh (f32 in ws) ------------
template<bool F32>
__device__ __forceinline__ void mlp_body(
    const void* __restrict__ TX,
    const void* __restrict__ Wd1, const void* __restrict__ bd1,
    const void* __restrict__ Wd2, const void* __restrict__ bd2,
    const void* __restrict__ Ws1, const void* __restrict__ bs1,
    const void* __restrict__ Ws2, const void* __restrict__ bs2,
    float* __restrict__ drift, float* __restrict__ Dh)
{
    __shared__ float sW[6][H_];
    const int tid = threadIdx.x;
    if (tid < H_) {
        sW[0][tid] = ld1<F32>(Wd1, tid);
        sW[1][tid] = ld1<F32>(bd1, tid);
        sW[2][tid] = ld1<F32>(Wd2, tid);
        sW[3][tid] = ld1<F32>(Ws1, tid);
        sW[4][tid] = ld1<F32>(bs1, tid);
        sW[5][tid] = ld1<F32>(Ws2, tid);
    }
    __syncthreads();
    const int i = blockIdx.x * 256 + tid;
    if (i >= TND) return;
    const float x = ld1<F32>(TX, i);
    float accd = 0.f, accs = 0.f;
#pragma unroll 10
    for (int h = 0; h < H_; ++h) {
        accd += tanhf(fmaf(x, sW[0][h], sW[1][h])) * sW[2][h];
        accs += tanhf(fmaf(x, sW[3][h], sW[4][h])) * sW[5][h];
    }
    drift[i] = accd + ld1<F32>(bd2, 0);
    Dh[i]    = 0.5f * (accs + ld1<F32>(bs2, 0));
}

__global__ __launch_bounds__(256) void mlp_kernel(
    const void* TX,
    const void* Wd1, const void* bd1, const void* Wd2, const void* bd2,
    const void* Ws1, const void* bs1, const void* Ws2, const void* bs2,
    const void* t, float* drift, float* Dh)
{
    // dtype sentinel: t[0]==0.0f -> first u32 is 0 under f32 layout,
    // 0x3C240000 (bf16(0.0), bf16(0.01)) under bf16 layout. Grid-uniform.
    if (((const unsigned*)t)[0] == 0u)
        mlp_body<true>(TX, Wd1, bd1, Wd2, bd2, Ws1, bs1, Ws2, bs2, drift, Dh);
    else
        mlp_body<false>(TX, Wd1, bd1, Wd2, bd2, Ws1, bs1, Ws2, bs2, drift, Dh);
}

// ---------------- Kernel 2: projections + output ----------------------------
// One block per (t', chunk of GB g-values). drift/Dh fragments are loaded
// into registers ONCE per block and reused across the GB gauss streams,
// cutting per-CU vector-memory traffic from 780 MB to ~492 MB per pass.
template<bool F32>
__device__ __forceinline__ void proj_body(
    const void* __restrict__ gn0,  const void* __restrict__ gn1,
    const void* __restrict__ gn2,  const void* __restrict__ gp11,
    const void* __restrict__ gp12, const void* __restrict__ gp20,
    const void* __restrict__ gp21, const void* __restrict__ gp22,
    const float* __restrict__ drift, const float* __restrict__ Dh,
    const void* __restrict__ t, void* __restrict__ out)
{
    const int b    = blockIdx.x;
    const int tp   = b % TM2;            // t' in [0, 50)
    const int g0   = (b / TM2) * GB;     // first g of this block's chunk
    const int tid  = threadIdx.x;
    const int wave = tid >> 6, lane = tid & 63;

    __shared__ float sA[GB][4], sB[GB][4];

    const bool main_act = (tid < ND / 8);   // 250 vec8 threads
    const bool b_act    = (tid < N_ / 8);   // 125 vec8 threads

    // Resident drift/Dh fragments (rows t', t'+1, t'+2): 6 x float8 = 48 VGPR
    float8_t d0, h0, d1, h1, d2, h2;
    if (main_act) {
        const int cb = tp * ND + tid * 8;
        d0 = *(const float8_t*)(drift + cb);
        h0 = *(const float8_t*)(Dh    + cb);
        d1 = *(const float8_t*)(drift + cb + ND);
        h1 = *(const float8_t*)(Dh    + cb + ND);
        d2 = *(const float8_t*)(drift + cb + 2 * ND);
        h2 = *(const float8_t*)(Dh    + cb + 2 * ND);
    }

    const int gbase = (g0 * TM2 + tp) * ND + tid * 8;
    const int bbase = (g0 * TM2 + tp) * N_ + tid * 8;

#pragma unroll 1   // keep transient load regs bounded; avoid spill from full unroll
    for (int gi = 0; gi < GB; ++gi) {
        float acc = 0.f, bacc = 0.f;
        if (main_act) {
            const int base = gbase + gi * (TM2 * ND);
            const float8_t a1 = ld8<F32>(gn1,  base);
            const float8_t a2 = ld8<F32>(gn2,  base);
            const float8_t b1 = ld8<F32>(gp11, base);
            const float8_t b2 = ld8<F32>(gp12, base);
            const float8_t c1 = ld8<F32>(gp21, base);
            const float8_t c2 = ld8<F32>(gp22, base);
#pragma unroll
            for (int j = 0; j < 8; ++j) {
                acc += a1[j] * d0[j] + a2[j] * h0[j]
                     + 4.f * (b1[j] * d1[j] + b2[j] * h1[j])
                     + c1[j] * d2[j] + c2[j] * h2[j];
            }
        }
        if (b_act) {
            const int bb = bbase + gi * (TM2 * N_);
            const float8_t z0 = ld8<F32>(gn0,  bb);
            const float8_t z2 = ld8<F32>(gp20, bb);
#pragma unroll
            for (int j = 0; j < 8; ++j) bacc += z2[j] - z0[j];
        }
        // wave (64) reduction; cross-wave merge deferred to one sync at end
#pragma unroll
        for (int off = 32; off > 0; off >>= 1) {
            acc  += __shfl_down(acc, off);
            bacc += __shfl_down(bacc, off);
        }
        if (lane == 0) { sA[gi][wave] = acc; sB[gi][wave] = bacc; }
    }
    __syncthreads();
    if (tid < GB) {
        const float A = sA[tid][0] + sA[tid][1] + sA[tid][2] + sA[tid][3];
        const float B = sB[tid][0] + sB[tid][1] + sB[tid][2] + sB[tid][3];
        const float dt = (ld1<F32>(t, T_ - 1) - ld1<F32>(t, 0)) * (1.0f / (T_ - 1));
        const float val = A * (dt / (3.0f * (float)N_)) - B * (1.0f / (float)N_);
        const int og = (g0 + tid) * TM2 + tp;
        if constexpr (F32) ((float*)out)[og] = val;
        else               ((unsigned short*)out)[og] = f2bf(val);
    }
}

__global__ __launch_bounds__(256) void proj_kernel(
    const void* gn0,  const void* gn1,  const void* gn2,
    const void* gp11, const void* gp12, const void* gp20,
    const void* gp21, const void* gp22,
    const float* drift, const float* Dh,
    const void* t, void* out)
{
    if (((const unsigned*)t)[0] == 0u)
        proj_body<true>(gn0, gn1, gn2, gp11, gp12, gp20, gp21, gp22,
                        drift, Dh, t, out);
    else
        proj_body<false>(gn0, gn1, gn2, gp11, gp12, gp20, gp21, gp22,
                         drift, Dh, t, out);
}

extern "C" void kernel_launch(void* const* d_in, const int* in_sizes, int n_in,
                              void* d_out, int out_size, void* d_ws, size_t ws_size,
                              hipStream_t stream) {
    const void* TX   = d_in[0];
    const void* t    = d_in[1];
    const void* gn0  = d_in[2];
    const void* gn1  = d_in[3];
    const void* gn2  = d_in[4];
    const void* gp11 = d_in[5];
    const void* gp12 = d_in[6];
    const void* gp20 = d_in[7];
    const void* gp21 = d_in[8];
    const void* gp22 = d_in[9];
    const void* Wd1  = d_in[10];
    const void* bd1  = d_in[11];
    const void* Wd2  = d_in[12];
    const void* bd2  = d_in[13];
    const void* Ws1  = d_in[14];
    const void* bs1  = d_in[15];
    const void* Ws2  = d_in[16];
    const void* bs2  = d_in[17];

    float* drift = (float*)d_ws;           // TND f32
    float* Dh    = drift + TND;            // TND f32  (832 KB total)

    mlp_kernel<<<(TND + 255) / 256, 256, 0, stream>>>(
        TX, Wd1, bd1, Wd2, bd2, Ws1, bs1, Ws2, bs2, t, drift, Dh);

    proj_kernel<<<NCHUNK * TM2, 256, 0, stream>>>(
        gn0, gn1, gn2, gp11, gp12, gp20, gp21, gp22, drift, Dh, t,
        (void*)d_out);
}

// Round 2
// 402.776 us; speedup vs baseline: 1.0031x; 1.0031x over previous
//
#include <hip/hip_runtime.h>
#include <hip/hip_bf16.h>

// Problem constants (fixed by the reference): T=52, N=1000, D=2, G=150, H=50
#define T_   52
#define N_   1000
#define D_   2
#define G_   150
#define H_   50
#define TM2  (T_ - 2)        // 50
#define ND   (N_ * D_)       // 2000
#define TND  (T_ * N_ * D_)  // 104000
#define GB   5               // g-values per block (G_ % GB == 0)
#define NCHUNK (G_ / GB)     // 30

typedef unsigned short ushort8_t __attribute__((ext_vector_type(8))); // 16 B
typedef float          float8_t  __attribute__((ext_vector_type(8))); // 32 B

__device__ __forceinline__ float bf2f(unsigned short u) {
    return __uint_as_float(((unsigned)u) << 16);
}
__device__ __forceinline__ unsigned short f2bf(float f) {
    unsigned u = __float_as_uint(f);
    u += 0x7fffu + ((u >> 16) & 1u);   // round-to-nearest-even
    return (unsigned short)(u >> 16);
}

// dtype-dispatched scalar load
template<bool F32>
__device__ __forceinline__ float ld1(const void* p, int i) {
    if constexpr (F32) return ((const float*)p)[i];
    else               return bf2f(((const unsigned short*)p)[i]);
}

// dtype-dispatched 8-element vector load (f32: 32B = 2x dwordx4; bf16: 16B)
template<bool F32>
__device__ __forceinline__ float8_t ld8(const void* p, int i) {
    if constexpr (F32) {
        return *(const float8_t*)((const float*)p + i);
    } else {
        ushort8_t v = *(const ushort8_t*)((const unsigned short*)p + i);
        float8_t r;
#pragma unroll
        for (int j = 0; j < 8; ++j) r[j] = bf2f(v[j]);
        return r;
    }
}

// ---------------- Kernel 1: scalar MLPs -> drift, Dh (f32 in ws) ------------
template<bool F32>
__device__ __forceinline__ void mlp_body(
    const void* __restrict__ TX,
    const void* __restrict__ Wd1, const void* __restrict__ bd1,
    const void* __restrict__ Wd2, const void* __restrict__ bd2,
    const void* __restrict__ Ws1, const void* __restrict__ bs1,
    const void* __restrict__ Ws2, const void* __restrict__ bs2,
    float* __restrict__ drift, float* __restrict__ Dh)
{
    __shared__ float sW[6][H_];
    const int tid = threadIdx.x;
    if (tid < H_) {
        sW[0][tid] = ld1<F32>(Wd1, tid);
        sW[1][tid] = ld1<F32>(bd1, tid);
        sW[2][tid] = ld1<F32>(Wd2, tid);
        sW[3][tid] = ld1<F32>(Ws1, tid);
        sW[4][tid] = ld1<F32>(bs1, tid);
        sW[5][tid] = ld1<F32>(Ws2, tid);
    }
    __syncthreads();
    const int i = blockIdx.x * 256 + tid;
    if (i >= TND) return;
    const float x = ld1<F32>(TX, i);
    float accd = 0.f, accs = 0.f;
#pragma unroll 10
    for (int h = 0; h < H_; ++h) {
        accd += tanhf(fmaf(x, sW[0][h], sW[1][h])) * sW[2][h];
        accs += tanhf(fmaf(x, sW[3][h], sW[4][h])) * sW[5][h];
    }
    drift[i] = accd + ld1<F32>(bd2, 0);
    Dh[i]    = 0.5f * (accs + ld1<F32>(bs2, 0));
}

__global__ __launch_bounds__(256) void mlp_kernel(
    const void* TX,
    const void* Wd1, const void* bd1, const void* Wd2, const void* bd2,
    const void* Ws1, const void* bs1, const void* Ws2, const void* bs2,
    const void* t, float* drift, float* Dh)
{
    // dtype sentinel: t[0]==0.0f -> first u32 is 0 under f32 layout,
    // 0x3C240000 (bf16(0.0), bf16(0.01)) under bf16 layout. Grid-uniform.
    if (((const unsigned*)t)[0] == 0u)
        mlp_body<true>(TX, Wd1, bd1, Wd2, bd2, Ws1, bs1, Ws2, bs2, drift, Dh);
    else
        mlp_body<false>(TX, Wd1, bd1, Wd2, bd2, Ws1, bs1, Ws2, bs2, drift, Dh);
}

// ---------------- Kernel 2: projections + output ----------------------------
// One block per (t', chunk of GB g-values). drift/Dh fragments register-
// resident, reused across GB gauss streams (492 MB total delivered vs 780 MB
// for the per-(g,t') grid). The g-loop is FULLY UNROLLED with per-gi private
// accumulators and NO in-loop reduction, so all 30 main-path float8 loads are
// independent and the scheduler can batch them (restores per-wave MLP that
// the Round-1 serialized loop destroyed). One reduction phase at block end.
template<bool F32>
__device__ __forceinline__ void proj_body(
    const void* __restrict__ gn0,  const void* __restrict__ gn1,
    const void* __restrict__ gn2,  const void* __restrict__ gp11,
    const void* __restrict__ gp12, const void* __restrict__ gp20,
    const void* __restrict__ gp21, const void* __restrict__ gp22,
    const float* __restrict__ drift, const float* __restrict__ Dh,
    const void* __restrict__ t, void* __restrict__ out)
{
    const int b    = blockIdx.x;
    const int tp   = b % TM2;            // t' in [0, 50)
    const int g0   = (b / TM2) * GB;     // first g of this block's chunk
    const int tid  = threadIdx.x;
    const int wave = tid >> 6, lane = tid & 63;

    __shared__ float sA[GB][4], sB[GB][4];

    const bool main_act = (tid < ND / 8);   // 250 vec8 threads
    const bool b_act    = (tid < N_ / 8);   // 125 vec8 threads

    // Resident drift/Dh fragments (rows t', t'+1, t'+2): 6 x float8 = 48 VGPR
    float8_t d0, h0, d1, h1, d2, h2;
    if (main_act) {
        const int cb = tp * ND + tid * 8;
        d0 = *(const float8_t*)(drift + cb);
        h0 = *(const float8_t*)(Dh    + cb);
        d1 = *(const float8_t*)(drift + cb + ND);
        h1 = *(const float8_t*)(Dh    + cb + ND);
        d2 = *(const float8_t*)(drift + cb + 2 * ND);
        h2 = *(const float8_t*)(Dh    + cb + 2 * ND);
    }

    const int gbase = (g0 * TM2 + tp) * ND + tid * 8;
    const int bbase = (g0 * TM2 + tp) * N_ + tid * 8;

    float accA[GB];
    float accB[GB];
#pragma unroll
    for (int gi = 0; gi < GB; ++gi) { accA[gi] = 0.f; accB[gi] = 0.f; }

    // Fully unrolled; accumulators are independent per gi -> no loop-carried
    // dependency; loads across all iterations can be in flight together.
#pragma unroll
    for (int gi = 0; gi < GB; ++gi) {
        if (main_act) {
            const int base = gbase + gi * (TM2 * ND);
            const float8_t a1 = ld8<F32>(gn1,  base);
            const float8_t a2 = ld8<F32>(gn2,  base);
            const float8_t b1 = ld8<F32>(gp11, base);
            const float8_t b2 = ld8<F32>(gp12, base);
            const float8_t c1 = ld8<F32>(gp21, base);
            const float8_t c2 = ld8<F32>(gp22, base);
            float s = 0.f;
#pragma unroll
            for (int j = 0; j < 8; ++j) {
                s += a1[j] * d0[j] + a2[j] * h0[j]
                   + 4.f * (b1[j] * d1[j] + b2[j] * h1[j])
                   + c1[j] * d2[j] + c2[j] * h2[j];
            }
            accA[gi] = s;
        }
        if (b_act) {
            const int bb = bbase + gi * (TM2 * N_);
            const float8_t z0 = ld8<F32>(gn0,  bb);
            const float8_t z2 = ld8<F32>(gp20, bb);
            float s = 0.f;
#pragma unroll
            for (int j = 0; j < 8; ++j) s += z2[j] - z0[j];
            accB[gi] = s;
        }
    }

    // Single reduction phase, off the load critical path.
#pragma unroll
    for (int gi = 0; gi < GB; ++gi) {
        float a = accA[gi], bb = accB[gi];
#pragma unroll
        for (int off = 32; off > 0; off >>= 1) {
            a  += __shfl_down(a, off);
            bb += __shfl_down(bb, off);
        }
        if (lane == 0) { sA[gi][wave] = a; sB[gi][wave] = bb; }
    }
    __syncthreads();
    if (tid < GB) {
        const float A = sA[tid][0] + sA[tid][1] + sA[tid][2] + sA[tid][3];
        const float B = sB[tid][0] + sB[tid][1] + sB[tid][2] + sB[tid][3];
        const float dt = (ld1<F32>(t, T_ - 1) - ld1<F32>(t, 0)) * (1.0f / (T_ - 1));
        const float val = A * (dt / (3.0f * (float)N_)) - B * (1.0f / (float)N_);
        const int og = (g0 + tid) * TM2 + tp;
        if constexpr (F32) ((float*)out)[og] = val;
        else               ((unsigned short*)out)[og] = f2bf(val);
    }
}

__global__ __launch_bounds__(256) void proj_kernel(
    const void* gn0,  const void* gn1,  const void* gn2,
    const void* gp11, const void* gp12, const void* gp20,
    const void* gp21, const void* gp22,
    const float* drift, const float* Dh,
    const void* t, void* out)
{
    if (((const unsigned*)t)[0] == 0u)
        proj_body<true>(gn0, gn1, gn2, gp11, gp12, gp20, gp21, gp22,
                        drift, Dh, t, out);
    else
        proj_body<false>(gn0, gn1, gn2, gp11, gp12, gp20, gp21, gp22,
                         drift, Dh, t, out);
}

extern "C" void kernel_launch(void* const* d_in, const int* in_sizes, int n_in,
                              void* d_out, int out_size, void* d_ws, size_t ws_size,
                              hipStream_t stream) {
    const void* TX   = d_in[0];
    const void* t    = d_in[1];
    const void* gn0  = d_in[2];
    const void* gn1  = d_in[3];
    const void* gn2  = d_in[4];
    const void* gp11 = d_in[5];
    const void* gp12 = d_in[6];
    const void* gp20 = d_in[7];
    const void* gp21 = d_in[8];
    const void* gp22 = d_in[9];
    const void* Wd1  = d_in[10];
    const void* bd1  = d_in[11];
    const void* Wd2  = d_in[12];
    const void* bd2  = d_in[13];
    const void* Ws1  = d_in[14];
    const void* bs1  = d_in[15];
    const void* Ws2  = d_in[16];
    const void* bs2  = d_in[17];

    float* drift = (float*)d_ws;           // TND f32
    float* Dh    = drift + TND;            // TND f32  (832 KB total)

    mlp_kernel<<<(TND + 255) / 256, 256, 0, stream>>>(
        TX, Wd1, bd1, Wd2, bd2, Ws1, bs1, Ws2, bs2, t, drift, Dh);

    proj_kernel<<<NCHUNK * TM2, 256, 0, stream>>>(
        gn0, gn1, gn2, gp11, gp12, gp20, gp21, gp22, drift, Dh, t,
        (void*)d_out);
}

// Round 3
// 397.238 us; speedup vs baseline: 1.0171x; 1.0139x over previous
//
#include <hip/hip_runtime.h>
#include <hip/hip_bf16.h>

// Problem constants (fixed by the reference): T=52, N=1000, D=2, G=150, H=50
#define T_   52
#define N_   1000
#define D_   2
#define G_   150
#define H_   50
#define TM2  (T_ - 2)        // 50
#define ND   (N_ * D_)       // 2000
#define TND  (T_ * N_ * D_)  // 104000
#define GB   5               // g-values per block (G_ % GB == 0)
#define NCHUNK (G_ / GB)     // 30

typedef unsigned short ushort8_t __attribute__((ext_vector_type(8))); // 16 B
typedef float          float8_t  __attribute__((ext_vector_type(8))); // 32 B

__device__ __forceinline__ float bf2f(unsigned short u) {
    return __uint_as_float(((unsigned)u) << 16);
}
__device__ __forceinline__ unsigned short f2bf(float f) {
    unsigned u = __float_as_uint(f);
    u += 0x7fffu + ((u >> 16) & 1u);   // round-to-nearest-even
    return (unsigned short)(u >> 16);
}

// dtype-dispatched scalar load
template<bool F32>
__device__ __forceinline__ float ld1(const void* p, int i) {
    if constexpr (F32) return ((const float*)p)[i];
    else               return bf2f(((const unsigned short*)p)[i]);
}

// dtype-dispatched 8-element vector load (f32: 32B = 2x dwordx4; bf16: 16B)
template<bool F32>
__device__ __forceinline__ float8_t ld8(const void* p, int i) {
    if constexpr (F32) {
        return *(const float8_t*)((const float*)p + i);
    } else {
        ushort8_t v = *(const ushort8_t*)((const unsigned short*)p + i);
        float8_t r;
#pragma unroll
        for (int j = 0; j < 8; ++j) r[j] = bf2f(v[j]);
        return r;
    }
}

// ---------------- Kernel 1: scalar MLPs -> drift, Dh (f32 in ws) ------------
template<bool F32>
__device__ __forceinline__ void mlp_body(
    const void* __restrict__ TX,
    const void* __restrict__ Wd1, const void* __restrict__ bd1,
    const void* __restrict__ Wd2, const void* __restrict__ bd2,
    const void* __restrict__ Ws1, const void* __restrict__ bs1,
    const void* __restrict__ Ws2, const void* __restrict__ bs2,
    float* __restrict__ drift, float* __restrict__ Dh)
{
    __shared__ float sW[6][H_];
    const int tid = threadIdx.x;
    if (tid < H_) {
        sW[0][tid] = ld1<F32>(Wd1, tid);
        sW[1][tid] = ld1<F32>(bd1, tid);
        sW[2][tid] = ld1<F32>(Wd2, tid);
        sW[3][tid] = ld1<F32>(Ws1, tid);
        sW[4][tid] = ld1<F32>(bs1, tid);
        sW[5][tid] = ld1<F32>(Ws2, tid);
    }
    __syncthreads();
    const int i = blockIdx.x * 256 + tid;
    if (i >= TND) return;
    const float x = ld1<F32>(TX, i);
    float accd = 0.f, accs = 0.f;
#pragma unroll 10
    for (int h = 0; h < H_; ++h) {
        accd += tanhf(fmaf(x, sW[0][h], sW[1][h])) * sW[2][h];
        accs += tanhf(fmaf(x, sW[3][h], sW[4][h])) * sW[5][h];
    }
    drift[i] = accd + ld1<F32>(bd2, 0);
    Dh[i]    = 0.5f * (accs + ld1<F32>(bs2, 0));
}

__global__ __launch_bounds__(256) void mlp_kernel(
    const void* TX,
    const void* Wd1, const void* bd1, const void* Wd2, const void* bd2,
    const void* Ws1, const void* bs1, const void* Ws2, const void* bs2,
    const void* t, float* drift, float* Dh)
{
    // dtype sentinel: t[0]==0.0f -> first u32 is 0 under f32 layout,
    // 0x3C240000 (bf16(0.0), bf16(0.01)) under bf16 layout. Grid-uniform.
    if (((const unsigned*)t)[0] == 0u)
        mlp_body<true>(TX, Wd1, bd1, Wd2, bd2, Ws1, bs1, Ws2, bs2, drift, Dh);
    else
        mlp_body<false>(TX, Wd1, bd1, Wd2, bd2, Ws1, bs1, Ws2, bs2, drift, Dh);
}

// ---------------- Kernel 2: projections + output ----------------------------
// One block per (t', chunk of GB g-values). drift/Dh register-resident and
// reused across GB gauss streams (492 MB delivered vs 780 MB for the
// per-(g,t') grid). Round-2 lesson: with default launch bounds the allocator
// clamped to 60 VGPR -> ~1.5 loads in flight per wave -> MLP-bound at the
// same 132 us. Fix: __launch_bounds__(256,2) (VGPR cap 256) + explicit load
// batching: 10 b-path loads upfront, main path depth-2 software pipeline.
// All array indices compile-time constant under full unroll (no scratch).
template<bool F32>
__device__ __forceinline__ void proj_body(
    const void* __restrict__ gn0,  const void* __restrict__ gn1,
    const void* __restrict__ gn2,  const void* __restrict__ gp11,
    const void* __restrict__ gp12, const void* __restrict__ gp20,
    const void* __restrict__ gp21, const void* __restrict__ gp22,
    const float* __restrict__ drift, const float* __restrict__ Dh,
    const void* __restrict__ t, void* __restrict__ out)
{
    const int b    = blockIdx.x;
    const int tp   = b % TM2;            // t' in [0, 50)
    const int g0   = (b / TM2) * GB;     // first g of this block's chunk
    const int tid  = threadIdx.x;
    const int wave = tid >> 6, lane = tid & 63;

    __shared__ float sA[GB][4], sB[GB][4];

    const bool main_act = (tid < ND / 8);   // 250 vec8 threads
    const bool b_act    = (tid < N_ / 8);   // 125 vec8 threads

    const int gbase = (g0 * TM2 + tp) * ND + tid * 8;
    const int bbase = (g0 * TM2 + tp) * N_ + tid * 8;

    // ---- b-path: issue ALL 10 loads upfront (80 VGPR transient) ----
    float8_t z0[GB], z2[GB];
    if (b_act) {
#pragma unroll
        for (int gi = 0; gi < GB; ++gi) {
            z0[gi] = ld8<F32>(gn0,  bbase + gi * (TM2 * N_));
            z2[gi] = ld8<F32>(gp20, bbase + gi * (TM2 * N_));
        }
    }

    // ---- resident drift/Dh fragments (48 VGPR) ----
    float8_t d0, h0, d1, h1, d2, h2;
    if (main_act) {
        const int cb = tp * ND + tid * 8;
        d0 = *(const float8_t*)(drift + cb);
        h0 = *(const float8_t*)(Dh    + cb);
        d1 = *(const float8_t*)(drift + cb + ND);
        h1 = *(const float8_t*)(Dh    + cb + ND);
        d2 = *(const float8_t*)(drift + cb + 2 * ND);
        h2 = *(const float8_t*)(Dh    + cb + 2 * ND);
    }

    // ---- main path: depth-2 software pipeline over gi ----
    float8_t A1[2], A2[2], B1[2], B2[2], C1[2], C2[2];  // 96 VGPR
    float accA[GB];
#pragma unroll
    for (int gi = 0; gi < GB; ++gi) accA[gi] = 0.f;

    if (main_act) {
        // prologue: issue loads for gi=0
        {
            const int base = gbase;
            A1[0] = ld8<F32>(gn1,  base);
            A2[0] = ld8<F32>(gn2,  base);
            B1[0] = ld8<F32>(gp11, base);
            B2[0] = ld8<F32>(gp12, base);
            C1[0] = ld8<F32>(gp21, base);
            C2[0] = ld8<F32>(gp22, base);
        }
#pragma unroll
        for (int gi = 0; gi < GB; ++gi) {
            const int cur = gi & 1;
            const int nxt = (gi + 1) & 1;
            if (gi + 1 < GB) {          // prefetch next g before consuming cur
                const int base = gbase + (gi + 1) * (TM2 * ND);
                A1[nxt] = ld8<F32>(gn1,  base);
                A2[nxt] = ld8<F32>(gn2,  base);
                B1[nxt] = ld8<F32>(gp11, base);
                B2[nxt] = ld8<F32>(gp12, base);
                C1[nxt] = ld8<F32>(gp21, base);
                C2[nxt] = ld8<F32>(gp22, base);
            }
            float s = 0.f;
#pragma unroll
            for (int j = 0; j < 8; ++j) {
                s += A1[cur][j] * d0[j] + A2[cur][j] * h0[j]
                   + 4.f * (B1[cur][j] * d1[j] + B2[cur][j] * h1[j])
                   + C1[cur][j] * d2[j] + C2[cur][j] * h2[j];
            }
            accA[gi] = s;
        }
    }

    // ---- b-path accumulate (loads issued long ago; latency already hidden) --
    float accB[GB];
#pragma unroll
    for (int gi = 0; gi < GB; ++gi) accB[gi] = 0.f;
    if (b_act) {
#pragma unroll
        for (int gi = 0; gi < GB; ++gi) {
            float s = 0.f;
#pragma unroll
            for (int j = 0; j < 8; ++j) s += z2[gi][j] - z0[gi][j];
            accB[gi] = s;
        }
    }

    // ---- single reduction phase at block end ----
#pragma unroll
    for (int gi = 0; gi < GB; ++gi) {
        float a = accA[gi], bb = accB[gi];
#pragma unroll
        for (int off = 32; off > 0; off >>= 1) {
            a  += __shfl_down(a, off);
            bb += __shfl_down(bb, off);
        }
        if (lane == 0) { sA[gi][wave] = a; sB[gi][wave] = bb; }
    }
    __syncthreads();
    if (tid < GB) {
        const float A = sA[tid][0] + sA[tid][1] + sA[tid][2] + sA[tid][3];
        const float B = sB[tid][0] + sB[tid][1] + sB[tid][2] + sB[tid][3];
        const float dt = (ld1<F32>(t, T_ - 1) - ld1<F32>(t, 0)) * (1.0f / (T_ - 1));
        const float val = A * (dt / (3.0f * (float)N_)) - B * (1.0f / (float)N_);
        const int og = (g0 + tid) * TM2 + tp;
        if constexpr (F32) ((float*)out)[og] = val;
        else               ((unsigned short*)out)[og] = f2bf(val);
    }
}

__global__ __launch_bounds__(256, 2) void proj_kernel(
    const void* gn0,  const void* gn1,  const void* gn2,
    const void* gp11, const void* gp12, const void* gp20,
    const void* gp21, const void* gp22,
    const float* drift, const float* Dh,
    const void* t, void* out)
{
    if (((const unsigned*)t)[0] == 0u)
        proj_body<true>(gn0, gn1, gn2, gp11, gp12, gp20, gp21, gp22,
                        drift, Dh, t, out);
    else
        proj_body<false>(gn0, gn1, gn2, gp11, gp12, gp20, gp21, gp22,
                         drift, Dh, t, out);
}

extern "C" void kernel_launch(void* const* d_in, const int* in_sizes, int n_in,
                              void* d_out, int out_size, void* d_ws, size_t ws_size,
                              hipStream_t stream) {
    const void* TX   = d_in[0];
    const void* t    = d_in[1];
    const void* gn0  = d_in[2];
    const void* gn1  = d_in[3];
    const void* gn2  = d_in[4];
    const void* gp11 = d_in[5];
    const void* gp12 = d_in[6];
    const void* gp20 = d_in[7];
    const void* gp21 = d_in[8];
    const void* gp22 = d_in[9];
    const void* Wd1  = d_in[10];
    const void* bd1  = d_in[11];
    const void* Wd2  = d_in[12];
    const void* bd2  = d_in[13];
    const void* Ws1  = d_in[14];
    const void* bs1  = d_in[15];
    const void* Ws2  = d_in[16];
    const void* bs2  = d_in[17];

    float* drift = (float*)d_ws;           // TND f32
    float* Dh    = drift + TND;            // TND f32  (832 KB total)

    mlp_kernel<<<(TND + 255) / 256, 256, 0, stream>>>(
        TX, Wd1, bd1, Wd2, bd2, Ws1, bs1, Ws2, bs2, t, drift, Dh);

    proj_kernel<<<NCHUNK * TM2, 256, 0, stream>>>(
        gn0, gn1, gn2, gp11, gp12, gp20, gp21, gp22, drift, Dh, t,
        (void*)d_out);
}